// Round 2
// baseline (283.280 us; speedup 1.0000x reference)
//
#include <hip/hip_runtime.h>
#include <cstdint>
#include <cstddef>

typedef __bf16 bf16;
typedef __bf16 bf16x8 __attribute__((ext_vector_type(8)));
typedef float  f32x4  __attribute__((ext_vector_type(4)));

#define B_  2
#define S_  2048
#define D_  1024
#define H_  16
#define KH  64

// ---------------------------------------------------------------------------
// async global->LDS, 16B per lane. LDS dest = wave-uniform base + lane*16.
// ---------------------------------------------------------------------------
__device__ __forceinline__ void gload_lds16(const bf16* gp, bf16* lds_base) {
    __builtin_amdgcn_global_load_lds(
        (const __attribute__((address_space(1))) unsigned int*)gp,
        (__attribute__((address_space(3))) unsigned int*)lds_base,
        16, 0, 0);
}

// ---------------------------------------------------------------------------
// Cast x (fp32) -> xb (bf16). 4 elements per thread.
// ---------------------------------------------------------------------------
__global__ __launch_bounds__(256) void cast_x(const float* __restrict__ x,
                                              bf16* __restrict__ xb)
{
    const int i = (blockIdx.x * 256 + threadIdx.x) * 4;
    const float4 v = *(const float4*)(x + i);
    union { int2 w; bf16 e[4]; } u;
    u.e[0] = (bf16)v.x; u.e[1] = (bf16)v.y; u.e[2] = (bf16)v.z; u.e[3] = (bf16)v.w;
    *(int2*)(xb + i) = u.w;
}

// ---------------------------------------------------------------------------
// Weight transpose + cast: W fp32 (1024x1024, k x n) -> WT bf16 (n x k).
// z = 0,1,2 -> WqkvT rows [z*1024, ...); z = 3 -> WoT.
// ---------------------------------------------------------------------------
__global__ __launch_bounds__(256) void transpose_w(
    const float* __restrict__ Wq, const float* __restrict__ Wk,
    const float* __restrict__ Wv, const float* __restrict__ Wo,
    bf16* __restrict__ WqkvT, bf16* __restrict__ WoT)
{
    __shared__ bf16 tl[64][72];
    const int z = blockIdx.z;
    const float* src = (z == 0) ? Wq : (z == 1) ? Wk : (z == 2) ? Wv : Wo;
    bf16* dst = (z < 3) ? (WqkvT + (size_t)z * D_ * D_) : WoT;
    const int r0 = blockIdx.y * 64;   // src row (k dim)
    const int c0 = blockIdx.x * 64;   // src col (n dim)
    const int t  = threadIdx.x;
    {
        const int r = t >> 2, cs = (t & 3) * 16;
        const float4* p = (const float4*)(src + (size_t)(r0 + r) * D_ + c0 + cs);
        float4 a0 = p[0], a1 = p[1], a2 = p[2], a3 = p[3];
        tl[cs +  0][r] = (bf16)a0.x; tl[cs +  1][r] = (bf16)a0.y;
        tl[cs +  2][r] = (bf16)a0.z; tl[cs +  3][r] = (bf16)a0.w;
        tl[cs +  4][r] = (bf16)a1.x; tl[cs +  5][r] = (bf16)a1.y;
        tl[cs +  6][r] = (bf16)a1.z; tl[cs +  7][r] = (bf16)a1.w;
        tl[cs +  8][r] = (bf16)a2.x; tl[cs +  9][r] = (bf16)a2.y;
        tl[cs + 10][r] = (bf16)a2.z; tl[cs + 11][r] = (bf16)a2.w;
        tl[cs + 12][r] = (bf16)a3.x; tl[cs + 13][r] = (bf16)a3.y;
        tl[cs + 14][r] = (bf16)a3.z; tl[cs + 15][r] = (bf16)a3.w;
    }
    __syncthreads();
    {
        const int c = t >> 2, rs = (t & 3) * 16;
        union { int4 v[2]; bf16 e[16]; } u;
#pragma unroll
        for (int i = 0; i < 16; ++i) u.e[i] = tl[c][rs + i];
        int4* p = (int4*)(dst + (size_t)(c0 + c) * D_ + r0 + rs);
        p[0] = u.v[0]; p[1] = u.v[1];
    }
}

// ---------------------------------------------------------------------------
// GEMM C = A(MxKd) * BT(NxKd)^T, bf16 in, fp32 accum.
// 128x128 block tile, BK=64, 4 waves (2x2), 16x16x32 MFMA, global_load_lds.
// EPI=0: fp32 row-major store into C.
// EPI=1: QKV scatter into (B,H,S,64) bf16 q/k/v; q scaled by 0.125.
// ---------------------------------------------------------------------------
template <int EPI>
__global__ __launch_bounds__(256, 2) void gemm_bt(
    const bf16* __restrict__ A, const bf16* __restrict__ BT,
    float* __restrict__ C, int N, int Kd,
    bf16* __restrict__ qp, bf16* __restrict__ kp, bf16* __restrict__ vp)
{
    __shared__ bf16 As[128 * 64];
    __shared__ bf16 Bs[128 * 64];
    const int tid  = threadIdx.x;
    const int lane = tid & 63;
    const int wave = tid >> 6;
    const int l15  = lane & 15;
    const int quad = lane >> 4;
    const int m0 = blockIdx.y * 128;
    const int n0 = blockIdx.x * 128;
    const int wm = (wave >> 1) * 64;
    const int wn = (wave & 1) * 64;

    f32x4 acc[4][4];
#pragma unroll
    for (int i = 0; i < 4; ++i)
#pragma unroll
        for (int j = 0; j < 4; ++j) acc[i][j] = f32x4{0.f, 0.f, 0.f, 0.f};

    for (int k0 = 0; k0 < Kd; k0 += 64) {
        __syncthreads();
#pragma unroll
        for (int c = 0; c < 4; ++c) {
            const int base  = wave * 4096 + c * 1024;  // byte offset in 16KB tile
            const int flatb = base + lane * 16;
            const int row   = flatb >> 7;              // 128B per tile row
            const int col   = (flatb & 127) >> 1;      // element col in [0,64)
            gload_lds16(A  + (size_t)(m0 + row) * Kd + k0 + col, As + (base >> 1));
            gload_lds16(BT + (size_t)(n0 + row) * Kd + k0 + col, Bs + (base >> 1));
        }
        __syncthreads();
#pragma unroll
        for (int kk = 0; kk < 64; kk += 32) {
            bf16x8 af[4], bfv[4];
#pragma unroll
            for (int i = 0; i < 4; ++i)
                af[i] = *(const bf16x8*)&As[(wm + i * 16 + l15) * 64 + kk + quad * 8];
#pragma unroll
            for (int j = 0; j < 4; ++j)
                bfv[j] = *(const bf16x8*)&Bs[(wn + j * 16 + l15) * 64 + kk + quad * 8];
#pragma unroll
            for (int i = 0; i < 4; ++i)
#pragma unroll
                for (int j = 0; j < 4; ++j)
                    acc[i][j] = __builtin_amdgcn_mfma_f32_16x16x32_bf16(
                        af[i], bfv[j], acc[i][j], 0, 0, 0);
        }
    }

#pragma unroll
    for (int i = 0; i < 4; ++i)
#pragma unroll
        for (int j = 0; j < 4; ++j) {
            const int Rb = m0 + wm + i * 16 + quad * 4;   // + reg
            const int Cc = n0 + wn + j * 16 + l15;
#pragma unroll
            for (int r = 0; r < 4; ++r) {
                const float v   = acc[i][j][r];
                const int   row = Rb + r;
                if (EPI == 0) {
                    C[(size_t)row * N + Cc] = v;
                } else {
                    const int sec = Cc >> 10, cc = Cc & 1023;
                    const int h = cc >> 6, kd = cc & 63;
                    const int b = row >> 11, s = row & (S_ - 1);
                    const size_t dst = ((size_t)(b * H_ + h) * S_ + s) * KH + kd;
                    if (sec == 0)      qp[dst] = (bf16)(v * 0.125f);  // 1/sqrt(64)
                    else if (sec == 1) kp[dst] = (bf16)v;
                    else               vp[dst] = (bf16)v;
                }
            }
        }
}

// ---------------------------------------------------------------------------
// RoPE on first 32 dims of each 64-dim head row, in place, q and k.
// One thread per (tensor,row). sin/cos stay fp32 (reference x.dtype=fp32).
// ---------------------------------------------------------------------------
__global__ __launch_bounds__(256) void rope_qk(bf16* __restrict__ q, bf16* __restrict__ k)
{
    const int tid   = blockIdx.x * blockDim.x + threadIdx.x;  // 131072
    const int which = tid >> 16;
    const int rem   = tid & 65535;            // bh*S + s
    const int s     = rem & (S_ - 1);
    bf16* p = (which ? k : q) + (size_t)rem * KH;
    union { int4 v[4]; bf16 e[32]; } u;
    int4* pv = (int4*)p;
#pragma unroll
    for (int i = 0; i < 4; ++i) u.v[i] = pv[i];
    const float l2_10000 = 13.28771237954945f;  // log2(10000)
#pragma unroll
    for (int i = 0; i < 16; ++i) {
        const float inv = exp2f(-(float)i * (l2_10000 / 16.f));
        const float ang = (float)s * inv;
        const float sb = sinf(ang);
        const float cb = cosf(ang);
        const float x0 = (float)u.e[2 * i], x1 = (float)u.e[2 * i + 1];
        u.e[2 * i]     = (bf16)(x0 * cb - x1 * sb);
        u.e[2 * i + 1] = (bf16)(x1 * cb + x0 * sb);
    }
#pragma unroll
    for (int i = 0; i < 4; ++i) pv[i] = u.v[i];
}

// ---------------------------------------------------------------------------
// V transpose per (b,h): (S,64) -> (64,S), 64x64 LDS tiles.
// ---------------------------------------------------------------------------
__global__ __launch_bounds__(256) void vtrans(const bf16* __restrict__ v, bf16* __restrict__ vt)
{
    __shared__ bf16 tl[64][72];
    const int jt = blockIdx.x, bh = blockIdx.y;
    const int j0 = jt * 64;
    const int t  = threadIdx.x;
    {
        const int r = t >> 2, cs = (t & 3) * 16;  // r: token, cs: dim
        union { int4 vv[2]; bf16 e[16]; } u;
        const int4* p = (const int4*)(v + ((size_t)bh * S_ + j0 + r) * KH + cs);
        u.vv[0] = p[0]; u.vv[1] = p[1];
#pragma unroll
        for (int i = 0; i < 16; ++i) tl[cs + i][r] = u.e[i];
    }
    __syncthreads();
    {
        const int c = t >> 2, rs = (t & 3) * 16;  // c: dim, rs: token
        union { int4 vv[2]; bf16 e[16]; } u;
#pragma unroll
        for (int i = 0; i < 16; ++i) u.e[i] = tl[c][rs + i];
        int4* p = (int4*)(vt + ((size_t)bh * KH + c) * S_ + j0 + rs);
        p[0] = u.vv[0]; p[1] = u.vv[1];
    }
}

// ---------------------------------------------------------------------------
// Flash attention. Block = one (b,h) x 64 q-rows; 4 waves x 16 rows each.
// q,k in (B,H,S,64); vt in (B,H,64,S); y out in (B,S,D) bf16.
// Online softmax in fp32; P goes C-layout -> LDS -> A-layout.
// ---------------------------------------------------------------------------
__global__ __launch_bounds__(256, 2) void attn(
    const bf16* __restrict__ q, const bf16* __restrict__ k,
    const bf16* __restrict__ vt, bf16* __restrict__ y)
{
    __shared__ bf16 Qs[64][72];
    __shared__ bf16 Ks[64][72];
    __shared__ bf16 VTs[64][72];
    __shared__ bf16 Ps[64][72];

    const int qt = blockIdx.x;       // q tile (64 rows)
    const int bh = blockIdx.y;       // b*H + h
    const int b  = bh >> 4, h = bh & 15;
    const int t    = threadIdx.x;
    const int lane = t & 63, wave = t >> 6;
    const int l15  = lane & 15, quad = lane >> 4;
    const int qbase = qt * 64;

    {   // stage Q tile once
        const int r = t >> 2, cs = (t & 3) * 16;
        const int4* p = (const int4*)(q + ((size_t)bh * S_ + qbase + r) * KH + cs);
        int4 a0 = p[0], a1 = p[1];
        *(int4*)&Qs[r][cs]     = a0;
        *(int4*)&Qs[r][cs + 8] = a1;
    }

    f32x4 accO[4];
    float mrow[4], lrow[4];
#pragma unroll
    for (int i = 0; i < 4; ++i) {
        accO[i] = f32x4{0.f, 0.f, 0.f, 0.f};
        mrow[i] = -__builtin_inff();
        lrow[i] = 0.f;
    }

    for (int jt = 0; jt <= qt; ++jt) {
        const int j0 = jt * 64;
        __syncthreads();
        {   // stage K tile and VT tile
            const int r = t >> 2, cs = (t & 3) * 16;
            const int4* kp = (const int4*)(k + ((size_t)bh * S_ + j0 + r) * KH + cs);
            int4 a0 = kp[0], a1 = kp[1];
            *(int4*)&Ks[r][cs]     = a0;
            *(int4*)&Ks[r][cs + 8] = a1;
            const int4* vp = (const int4*)(vt + ((size_t)bh * KH + r) * S_ + j0 + cs);
            int4 b0 = vp[0], b1 = vp[1];
            *(int4*)&VTs[r][cs]     = b0;
            *(int4*)&VTs[r][cs + 8] = b1;
        }
        __syncthreads();

        // S = Q K^T  (wave's 16 rows x 64 keys)
        f32x4 accS[4];
#pragma unroll
        for (int nb = 0; nb < 4; ++nb) accS[nb] = f32x4{0.f, 0.f, 0.f, 0.f};
#pragma unroll
        for (int kk = 0; kk < 64; kk += 32) {
            const bf16x8 a = *(const bf16x8*)&Qs[wave * 16 + l15][kk + quad * 8];
#pragma unroll
            for (int nb = 0; nb < 4; ++nb) {
                const bf16x8 bb = *(const bf16x8*)&Ks[nb * 16 + l15][kk + quad * 8];
                accS[nb] = __builtin_amdgcn_mfma_f32_16x16x32_bf16(a, bb, accS[nb], 0, 0, 0);
            }
        }

        if (jt == qt) {  // causal mask only on the diagonal tile
#pragma unroll
            for (int nb = 0; nb < 4; ++nb)
#pragma unroll
                for (int r = 0; r < 4; ++r) {
                    const int qi = qbase + wave * 16 + quad * 4 + r;
                    const int ki = j0 + nb * 16 + l15;
                    if (ki > qi) accS[nb][r] = -__builtin_inff();
                }
        }

        // online softmax update (each row lives in 16 lanes of a quad)
#pragma unroll
        for (int r = 0; r < 4; ++r) {
            float mx = fmaxf(fmaxf(accS[0][r], accS[1][r]), fmaxf(accS[2][r], accS[3][r]));
            mx = fmaxf(mx, __shfl_xor(mx, 1));
            mx = fmaxf(mx, __shfl_xor(mx, 2));
            mx = fmaxf(mx, __shfl_xor(mx, 4));
            mx = fmaxf(mx, __shfl_xor(mx, 8));
            const float mn = fmaxf(mrow[r], mx);
            const float al = __expf(mrow[r] - mn);  // exp(-inf)=0 on first tile
            float psum = 0.f;
#pragma unroll
            for (int nb = 0; nb < 4; ++nb) {
                const float p = __expf(accS[nb][r] - mn);
                psum += p;
                Ps[wave * 16 + quad * 4 + r][nb * 16 + l15] = (bf16)p;
            }
            psum += __shfl_xor(psum, 1);
            psum += __shfl_xor(psum, 2);
            psum += __shfl_xor(psum, 4);
            psum += __shfl_xor(psum, 8);
            lrow[r] = lrow[r] * al + psum;
            mrow[r] = mn;
#pragma unroll
            for (int vb = 0; vb < 4; ++vb) accO[vb][r] *= al;
        }

        // O += P V   (P from LDS in A-layout, V^T rows contiguous)
#pragma unroll
        for (int kk = 0; kk < 64; kk += 32) {
            const bf16x8 a = *(const bf16x8*)&Ps[wave * 16 + l15][kk + quad * 8];
#pragma unroll
            for (int vb = 0; vb < 4; ++vb) {
                const bf16x8 bb = *(const bf16x8*)&VTs[vb * 16 + l15][kk + quad * 8];
                accO[vb] = __builtin_amdgcn_mfma_f32_16x16x32_bf16(a, bb, accO[vb], 0, 0, 0);
            }
        }
    }

    // normalize and store to y (B,S,D) with heads re-interleaved
#pragma unroll
    for (int vb = 0; vb < 4; ++vb)
#pragma unroll
        for (int r = 0; r < 4; ++r) {
            const int srow = qbase + wave * 16 + quad * 4 + r;
            const int col  = h * KH + vb * 16 + l15;
            y[((size_t)b * S_ + srow) * D_ + col] = (bf16)(accO[vb][r] / lrow[r]);
        }
}

// ---------------------------------------------------------------------------
extern "C" void kernel_launch(void* const* d_in, const int* in_sizes, int n_in,
                              void* d_out, int out_size, void* d_ws, size_t ws_size,
                              hipStream_t stream)
{
    (void)in_sizes; (void)n_in; (void)out_size; (void)ws_size;
    const float* x  = (const float*)d_in[0];
    // d_in[1] is the mask: deterministic tril -> causality handled by index
    const float* Wq = (const float*)d_in[2];
    const float* Wk = (const float*)d_in[3];
    const float* Wv = (const float*)d_in[4];
    const float* Wo = (const float*)d_in[5];
    float* out = (float*)d_out;

    char* ws = (char*)d_ws;
    bf16* WqkvT = (bf16*)(ws + 0);          //  6 MB: [Wq^T; Wk^T; Wv^T] (3072x1024)
    bf16* WoT   = (bf16*)(ws + 6291456);    //  2 MB
    bf16* xb    = (bf16*)(ws + 8388608);    //  8 MB (B*S, D) bf16
    bf16* qw    = (bf16*)(ws + 16777216);   //  8 MB (B,H,S,64)
    bf16* kw    = (bf16*)(ws + 25165824);   //  8 MB
    bf16* vw    = (bf16*)(ws + 33554432);   //  8 MB
    bf16* vtw   = (bf16*)(ws + 41943040);   //  8 MB (B,H,64,S)
    bf16* yw    = vw;                       //  v dead after vtrans; reuse for y

    hipLaunchKernelGGL(cast_x, dim3(4096), dim3(256), 0, stream, x, xb);
    hipLaunchKernelGGL(transpose_w, dim3(16, 16, 4), dim3(256), 0, stream,
                       Wq, Wk, Wv, Wo, WqkvT, WoT);
    hipLaunchKernelGGL((gemm_bt<1>), dim3(24, 32), dim3(256), 0, stream,
                       xb, WqkvT, (float*)nullptr, 3072, 1024, qw, kw, vw);
    hipLaunchKernelGGL(rope_qk, dim3(512), dim3(256), 0, stream, qw, kw);
    hipLaunchKernelGGL(vtrans, dim3(32, 32), dim3(256), 0, stream, vw, vtw);
    hipLaunchKernelGGL(attn, dim3(32, 32), dim3(256), 0, stream, qw, kw, vtw, yw);
    hipLaunchKernelGGL((gemm_bt<0>), dim3(8, 32), dim3(256), 0, stream,
                       yw, WoT, out, 1024, 1024,
                       (bf16*)nullptr, (bf16*)nullptr, (bf16*)nullptr);
}